// Round 10
// baseline (226.442 us; speedup 1.0000x reference)
//
#include <hip/hip_runtime.h>
#include <hip/hip_fp16.h>

#define N_NODES 100000
#define N_EDGES 3200000
#define NUM_FEATURES 128
#define DIM 10
#define NUM_GRAPHS 64

#define BSHIFT 8                             // 256 nodes per bucket
#define BSIZE (1 << BSHIFT)
#define NB ((N_NODES + BSIZE - 1) / BSIZE)   // 391 buckets
#define CHUNKS 4                             // spmm1 chunks per bucket
#define PCHUNKS 4                            // pass2 chunks per bucket
#define EPB 12500                            // edges per placement block
#define PLACE_BLOCKS 256                     // 256 * 12500 = 3.2M exact
#define NQUAD 25000                          // 100k nodes / 4 per 32-lane group
#define GEMM_BLOCKS 1563                     // ceil(25000*32 / 512)
#define BOUND_BLOCKS 196                     // ceil(100000 / 512)
#define TILE (BSIZE * DIM)                   // 2560 floats per bucket part tile
#define CAP 2560                             // max edges per spmm1 chunk (mean 2046, +22 sigma)
#define CAPB 16384                           // per-bucket pk region capacity (+90 sigma)
#define NCHUNK (NB * CHUNKS)                 // 1564
#define NCHUNK2 (NB * PCHUNKS)               // 1564
#define ACC_STRIDE 11
#define ROWH2 8                              // h1/r row = 8 half2 = 32B (10 real + 6 pad)

// f32 add of DPP row-rotated value (VALU pipe)
#define DPP_ROR_ADD(v, n)                                                        \
    (v) += __int_as_float(__builtin_amdgcn_update_dpp(                           \
        0, __float_as_int(v), 0x120 | (n), 0xF, 0xF, false))

// unpack a 16B row-half (4 half2) and accumulate into 8 fixed-index floats
__device__ __forceinline__ void acc8(const float4& q, float a[8]) {
    float2 u0 = __half22float2(__builtin_bit_cast(__half2, q.x));
    float2 u1 = __half22float2(__builtin_bit_cast(__half2, q.y));
    float2 u2 = __half22float2(__builtin_bit_cast(__half2, q.z));
    float2 u3 = __half22float2(__builtin_bit_cast(__half2, q.w));
    a[0] += u0.x; a[1] += u0.y; a[2] += u1.x; a[3] += u1.y;
    a[4] += u2.x; a[5] += u2.y; a[6] += u3.x; a[7] += u3.y;
}

// branchless dual-accumulator variant (graph A vs B)
__device__ __forceinline__ void selacc8(const float4& q, bool s, float aA[8], float aB[8]) {
    float2 u0 = __half22float2(__builtin_bit_cast(__half2, q.x));
    float2 u1 = __half22float2(__builtin_bit_cast(__half2, q.y));
    float2 u2 = __half22float2(__builtin_bit_cast(__half2, q.z));
    float2 u3 = __half22float2(__builtin_bit_cast(__half2, q.w));
    aA[0] += s ? u0.x : 0.f;  aB[0] += s ? 0.f : u0.x;
    aA[1] += s ? u0.y : 0.f;  aB[1] += s ? 0.f : u0.y;
    aA[2] += s ? u1.x : 0.f;  aB[2] += s ? 0.f : u1.x;
    aA[3] += s ? u1.y : 0.f;  aB[3] += s ? 0.f : u1.y;
    aA[4] += s ? u2.x : 0.f;  aB[4] += s ? 0.f : u2.x;
    aA[5] += s ? u2.y : 0.f;  aB[5] += s ? 0.f : u2.y;
    aA[6] += s ? u3.x : 0.f;  aB[6] += s ? 0.f : u3.x;
    aA[7] += s ? u3.y : 0.f;  aB[7] += s ? 0.f : u3.y;
}

// ---------------------------------------------------------------------------
// Fused front-end (R5-proven structure; GEMM output now 32B padded rows).
// R4/R7/R8/R9 lessons: k_front's GEMM half touches W1 once/thread already;
// its ~55us is intrinsic (TA + VALU + placement tail) — stop poking it.
// R3 lesson: no cross-block fences/fusion. R6: no pk line-padding.
// ---------------------------------------------------------------------------
__global__ __launch_bounds__(512) void k_front(const float* __restrict__ feat,
                                               const float* __restrict__ W1,
                                               __half* __restrict__ h1,
                                               const int* __restrict__ gids,
                                               int* __restrict__ bound,
                                               const int* __restrict__ src,
                                               const int* __restrict__ dst,
                                               int* __restrict__ cnt,
                                               int* __restrict__ pk) {
    __shared__ int hd[NB];      // placement: per-block histogram
    __shared__ int cb[NB];      // placement: absolute write cursors

    if (blockIdx.x < PLACE_BLOCKS) {
        int base0 = blockIdx.x * EPB;
        for (int t = threadIdx.x; t < NB; t += 512) hd[t] = 0;
        __syncthreads();

        // phase 1: histogram (coalesced 4-batched dst loads)
        {
            int i = threadIdx.x;
            for (; i + 1536 < EPB; i += 2048) {
                int d0 = dst[base0 + i],        d1 = dst[base0 + i + 512];
                int d2 = dst[base0 + i + 1024], d3 = dst[base0 + i + 1536];
                atomicAdd(&hd[d0 >> BSHIFT], 1);
                atomicAdd(&hd[d1 >> BSHIFT], 1);
                atomicAdd(&hd[d2 >> BSHIFT], 1);
                atomicAdd(&hd[d3 >> BSHIFT], 1);
            }
            for (; i < EPB; i += 512)
                atomicAdd(&hd[dst[base0 + i] >> BSHIFT], 1);
        }
        __syncthreads();

        // phase 2: reserve contiguous range in bucket region via global atomic
        for (int t = threadIdx.x; t < NB; t += 512) {
            int c = hd[t];
            int o = c ? atomicAdd(&cnt[t], c) : 0;
            cb[t] = t * CAPB + o;
        }
        __syncthreads();

        // phase 3: place (dst re-read is L2-hot; 1 LDS atomic/edge; clamp=safety)
        {
            int i = threadIdx.x;
            for (; i + 1536 < EPB; i += 2048) {
                int d0 = dst[base0 + i],        d1 = dst[base0 + i + 512];
                int d2 = dst[base0 + i + 1024], d3 = dst[base0 + i + 1536];
                int s0 = src[base0 + i],        s1 = src[base0 + i + 512];
                int s2 = src[base0 + i + 1024], s3 = src[base0 + i + 1536];
                int q0 = atomicAdd(&cb[d0 >> BSHIFT], 1);
                int q1 = atomicAdd(&cb[d1 >> BSHIFT], 1);
                int q2 = atomicAdd(&cb[d2 >> BSHIFT], 1);
                int q3 = atomicAdd(&cb[d3 >> BSHIFT], 1);
                if (q0 < ((d0 >> BSHIFT) + 1) * CAPB) pk[q0] = ((d0 & (BSIZE - 1)) << 17) | s0;
                if (q1 < ((d1 >> BSHIFT) + 1) * CAPB) pk[q1] = ((d1 & (BSIZE - 1)) << 17) | s1;
                if (q2 < ((d2 >> BSHIFT) + 1) * CAPB) pk[q2] = ((d2 & (BSIZE - 1)) << 17) | s2;
                if (q3 < ((d3 >> BSHIFT) + 1) * CAPB) pk[q3] = ((d3 & (BSIZE - 1)) << 17) | s3;
            }
            for (; i < EPB; i += 512) {
                int d = dst[base0 + i];
                int s = src[base0 + i];
                int q = atomicAdd(&cb[d >> BSHIFT], 1);
                if (q < ((d >> BSHIFT) + 1) * CAPB) pk[q] = ((d & (BSIZE - 1)) << 17) | s;
            }
        }
        return;
    }

    // ---- GEMM half: 4 nodes per 32-lane group ----
    int bb = blockIdx.x - PLACE_BLOCKS;

    // fused graph-boundary computation (gids sorted)
    int nb2 = bb * 512 + threadIdx.x;
    if (bb < BOUND_BLOCKS && nb2 < N_NODES) {
        int g  = gids[nb2];
        int gp = nb2 ? gids[nb2 - 1] : -1;
        for (int v = gp + 1; v <= g; ++v) bound[v] = nb2;
        if (nb2 == N_NODES - 1)
            for (int v = g + 1; v <= NUM_GRAPHS; ++v) bound[v] = N_NODES;
    }

    int gid  = bb * 512 + threadIdx.x;
    int quad = gid >> 5;                 // node quad id
    int lane = gid & 31;
    if (quad >= NQUAD) return;

    // lane's W1 slice (rows lane*4..lane*4+3, 160B contiguous) as 10 dwordx4
    float wf[40];
    {
        const float4* W14 = reinterpret_cast<const float4*>(W1 + lane * 40);
#pragma unroll
        for (int m = 0; m < 10; ++m) {
            float4 q = W14[m];
            wf[4 * m]     = q.x;
            wf[4 * m + 1] = q.y;
            wf[4 * m + 2] = q.z;
            wf[4 * m + 3] = q.w;
        }
    }

    int nbase = quad * 4;
    float4 f[4];
#pragma unroll
    for (int n = 0; n < 4; ++n)
        f[n] = *reinterpret_cast<const float4*>(feat + (size_t)(nbase + n) * NUM_FEATURES + lane * 4);

    float acc[4][DIM];
#pragma unroll
    for (int n = 0; n < 4; ++n)
#pragma unroll
        for (int k = 0; k < DIM; ++k) acc[n][k] = 0.f;

#pragma unroll
    for (int n = 0; n < 4; ++n) {
        float fv[4] = {f[n].x, f[n].y, f[n].z, f[n].w};
#pragma unroll
        for (int j = 0; j < 4; ++j)
#pragma unroll
            for (int k = 0; k < DIM; ++k)
                acc[n][k] += fv[j] * wf[j * DIM + k];
    }

    // reduce over 32 lanes: 4 in-row DPP rotate-adds (VALU) + 1 shfl_xor(16)
#pragma unroll
    for (int n = 0; n < 4; ++n)
#pragma unroll
        for (int k = 0; k < DIM; ++k) {
            float v = acc[n][k];
            DPP_ROR_ADD(v, 1);
            DPP_ROR_ADD(v, 2);
            DPP_ROR_ADD(v, 4);
            DPP_ROR_ADD(v, 8);
            acc[n][k] = v + __shfl_xor(v, 16);
        }

    if (lane == 0) {
        float4* o4 = (float4*)h1;
#pragma unroll
        for (int n = 0; n < 4; ++n) {
            float4 w0, w1;
            w0.x = __builtin_bit_cast(float, __floats2half2_rn(acc[n][0], acc[n][1]));
            w0.y = __builtin_bit_cast(float, __floats2half2_rn(acc[n][2], acc[n][3]));
            w0.z = __builtin_bit_cast(float, __floats2half2_rn(acc[n][4], acc[n][5]));
            w0.w = __builtin_bit_cast(float, __floats2half2_rn(acc[n][6], acc[n][7]));
            w1.x = __builtin_bit_cast(float, __floats2half2_rn(acc[n][8], acc[n][9]));
            w1.y = 0.f; w1.z = 0.f; w1.w = 0.f;          // zero pad halves 10..15
            o4[(size_t)(nbase + n) * 2 + 0] = w0;
            o4[(size_t)(nbase + n) * 2 + 1] = w1;
        }
    }
}

// ---------------------------------------------------------------------------
// Pass 1 SpMM. Sort phases as proven (eh stash, 2 LDS atomics/edge). Gather
// REDESIGNED for TA: 32B padded rows -> 2 lanes x dwordx4 per edge (was 5
// lanes x dword), 256 dedicated loc-walkers (all 64 lanes active, no loop).
// ---------------------------------------------------------------------------
__global__ __launch_bounds__(512) void k_spmm1(const __half* __restrict__ h,
                                               const int* __restrict__ cnt,
                                               const int* __restrict__ pk,
                                               float* __restrict__ part) {
    __shared__ int eh[CAP];
    __shared__ int srt[CAP];
    __shared__ int hist[BSIZE];
    __shared__ int cur[BSIZE];

    int b     = blockIdx.x / CHUNKS;
    int chunk = blockIdx.x % CHUNKS;
    int s0  = b * CAPB;
    int len = cnt[b];
    int c0  = s0 + (len * chunk) / CHUNKS;
    int c1  = s0 + (len * (chunk + 1)) / CHUNKS;
    int n   = c1 - c0;
    int nc  = min(n, CAP);

    for (int t = threadIdx.x; t < BSIZE; t += 512) hist[t] = 0;
    __syncthreads();

    {
        int i = threadIdx.x;
        for (; i + 1536 < nc; i += 2048) {
            int p0 = pk[c0 + i],        p1 = pk[c0 + i + 512];
            int p2 = pk[c0 + i + 1024], p3 = pk[c0 + i + 1536];
            eh[i] = p0; eh[i + 512] = p1; eh[i + 1024] = p2; eh[i + 1536] = p3;
            atomicAdd(&hist[p0 >> 17], 1);
            atomicAdd(&hist[p1 >> 17], 1);
            atomicAdd(&hist[p2 >> 17], 1);
            atomicAdd(&hist[p3 >> 17], 1);
        }
        for (; i < nc; i += 512) {
            int p = pk[c0 + i];
            eh[i] = p;
            atomicAdd(&hist[p >> 17], 1);
        }
    }
    __syncthreads();

    if (threadIdx.x < 64) {
        int l = threadIdx.x;
        int carry = 0;
#pragma unroll
        for (int j = 0; j < 4; ++j) {
            int x = hist[j * 64 + l];
            int v = x;
#pragma unroll
            for (int off = 1; off < 64; off <<= 1) {
                int t2 = __shfl_up(v, off);
                if (l >= off) v += t2;
            }
            cur[j * 64 + l] = carry + v - x;
            carry += __shfl(v, 63);
        }
    }
    __syncthreads();

    for (int i = threadIdx.x; i < nc; i += 512) {
        int p = eh[i];
        int pos = atomicAdd(&cur[p >> 17], 1);
        srt[pos] = p;
    }
    __syncthreads();

    int wave = threadIdx.x >> 6;
    int lane = threadIdx.x & 63;
    int slot = lane >> 1;           // 0..31
    int l    = lane & 1;            // which 16B half of the 32B row
    float* pb = part + (size_t)blockIdx.x * TILE;
    const float4* h4 = (const float4*)h;

    {
        int g  = wave * 32 + slot;  // 0..255: dedicated walker per loc
        int e0 = g ? cur[g - 1] : 0;
        int e1 = cur[g];
        float a[8]  = {0.f, 0.f, 0.f, 0.f, 0.f, 0.f, 0.f, 0.f};
        float b2[8] = {0.f, 0.f, 0.f, 0.f, 0.f, 0.f, 0.f, 0.f};
        int e = e0;
        for (; e + 7 < e1; e += 8) {
            float4 q0 = h4[(size_t)(srt[e]     & 0x1FFFF) * 2 + l];
            float4 q1 = h4[(size_t)(srt[e + 1] & 0x1FFFF) * 2 + l];
            float4 q2 = h4[(size_t)(srt[e + 2] & 0x1FFFF) * 2 + l];
            float4 q3 = h4[(size_t)(srt[e + 3] & 0x1FFFF) * 2 + l];
            float4 q4 = h4[(size_t)(srt[e + 4] & 0x1FFFF) * 2 + l];
            float4 q5 = h4[(size_t)(srt[e + 5] & 0x1FFFF) * 2 + l];
            float4 q6 = h4[(size_t)(srt[e + 6] & 0x1FFFF) * 2 + l];
            float4 q7 = h4[(size_t)(srt[e + 7] & 0x1FFFF) * 2 + l];
            acc8(q0, a); acc8(q1, b2); acc8(q2, a); acc8(q3, b2);
            acc8(q4, a); acc8(q5, b2); acc8(q6, a); acc8(q7, b2);
        }
        for (; e < e1; ++e)
            acc8(h4[(size_t)(srt[e] & 0x1FFFF) * 2 + l], a);
#pragma unroll
        for (int j = 0; j < 8; ++j) a[j] += b2[j];

        float2* pb2 = (float2*)pb;
        if (l == 0) {
            pb2[g * 5 + 0] = make_float2(a[0], a[1]);
            pb2[g * 5 + 1] = make_float2(a[2], a[3]);
            pb2[g * 5 + 2] = make_float2(a[4], a[5]);
            pb2[g * 5 + 3] = make_float2(a[6], a[7]);
        } else {
            pb2[g * 5 + 4] = make_float2(a[0], a[1]);   // d8,d9 (rest are pads)
        }
    }
    __syncthreads();

    // overflow fallback (statistically never; correctness guard)
    const __half2* h2f = (const __half2*)h;
    for (int i = CAP + threadIdx.x; i < n; i += 512) {
        int p = pk[c0 + i];
        int loc = p >> 17, s = p & 0x1FFFF;
#pragma unroll
        for (int j = 0; j < 5; ++j) {
            float2 v = __half22float2(h2f[(size_t)s * ROWH2 + j]);
            atomicAdd(&pb[loc * DIM + 2 * j], v.x);
            atomicAdd(&pb[loc * DIM + 2 * j + 1], v.y);
        }
    }
}

// merge CHUNKS partials + fused relu -> r (fp16, 32B padded rows)
__global__ __launch_bounds__(256) void k_merge_relu(const float* __restrict__ part,
                                                    __half* __restrict__ r) {
    int b     = blockIdx.x;
    int nbase = b << BSHIFT;
    const float* p0 = part + (size_t)(b * CHUNKS) * TILE;
    __half2* r2 = (__half2*)r;
    for (int t = threadIdx.x; t < BSIZE * ROWH2; t += 256) {
        int node = t >> 3;
        int j    = t & 7;
        int gn   = nbase + node;
        if (gn >= N_NODES) break;
        __half2 outv;
        if (j < 5) {
            float sx = 0.f, sy = 0.f;
#pragma unroll
            for (int c = 0; c < CHUNKS; ++c) {
                float2 v = ((const float2*)(p0 + (size_t)c * TILE))[node * 5 + j];
                sx += v.x; sy += v.y;
            }
            outv = __floats2half2_rn(fmaxf(sx, 0.f), fmaxf(sy, 0.f));
        } else {
            outv = __floats2half2_rn(0.f, 0.f);
        }
        r2[(size_t)gn * ROWH2 + j] = outv;
    }
}

// ---------------------------------------------------------------------------
// Pass 2. Same TA redesign: 2 lanes x dwordx4 per edge, 32 slots/wave,
// branchless dual accumulator, 4-deep batched loads, LDS-atomic flush.
// ---------------------------------------------------------------------------
__global__ __launch_bounds__(512) void k_pass2(const __half* __restrict__ r,
                                               const int* __restrict__ cnt,
                                               const int* __restrict__ pk,
                                               const int* __restrict__ bound,
                                               float* __restrict__ sums) {
    __shared__ float acc[NUM_GRAPHS * ACC_STRIDE];

    int b     = blockIdx.x / PCHUNKS;
    int chunk = blockIdx.x % PCHUNKS;
    int nbase = b << BSHIFT;
    int nlast = min(nbase + BSIZE - 1, N_NODES - 1);

    int glo = 0, ghx = NUM_GRAPHS - 1;
#pragma unroll
    for (int it = 0; it < 6; ++it) {
        int mid = (glo + ghx + 1) >> 1;
        if (bound[mid] <= nbase) glo = mid; else ghx = mid - 1;
    }
    int lo2 = 0, hi2 = NUM_GRAPHS - 1;
#pragma unroll
    for (int it = 0; it < 6; ++it) {
        int mid = (lo2 + hi2 + 1) >> 1;
        if (bound[mid] <= nlast) lo2 = mid; else hi2 = mid - 1;
    }
    int ghi  = lo2;
    int span = ghi - glo;

    for (int t = threadIdx.x; t < (span + 1) * DIM; t += 512)
        acc[(glo + t / DIM) * ACC_STRIDE + t % DIM] = 0.f;
    __syncthreads();

    int s0  = b * CAPB;
    int len = cnt[b];
    int c0  = s0 + (len * chunk) / PCHUNKS;
    int c1  = s0 + (len * (chunk + 1)) / PCHUNKS;

    int wave = threadIdx.x >> 6;
    int lane = threadIdx.x & 63;
    int slot = lane >> 1;
    int l    = lane & 1;
    const float4* r4 = (const float4*)r;

    {
        const int STR = 256;
        int q = wave * 32 + slot;
        int e = c0 + q;
        if (span <= 1) {
            int gA  = glo;
            int gB  = (span == 1) ? glo + 1 : glo;
            int cut = (span == 1) ? (bound[glo + 1] - nbase) : BSIZE;
            float aA[8] = {0.f, 0.f, 0.f, 0.f, 0.f, 0.f, 0.f, 0.f};
            float aB[8] = {0.f, 0.f, 0.f, 0.f, 0.f, 0.f, 0.f, 0.f};
            for (; e + 3 * STR < c1; e += 4 * STR) {
                int p0 = pk[e], p1 = pk[e + STR], p2 = pk[e + 2 * STR], p3 = pk[e + 3 * STR];
                float4 q0 = r4[(size_t)(p0 & 0x1FFFF) * 2 + l];
                float4 q1 = r4[(size_t)(p1 & 0x1FFFF) * 2 + l];
                float4 q2 = r4[(size_t)(p2 & 0x1FFFF) * 2 + l];
                float4 q3 = r4[(size_t)(p3 & 0x1FFFF) * 2 + l];
                selacc8(q0, (p0 >> 17) < cut, aA, aB);
                selacc8(q1, (p1 >> 17) < cut, aA, aB);
                selacc8(q2, (p2 >> 17) < cut, aA, aB);
                selacc8(q3, (p3 >> 17) < cut, aA, aB);
            }
            for (; e < c1; e += STR) {
                int p = pk[e];
                float4 qv = r4[(size_t)(p & 0x1FFFF) * 2 + l];
                selacc8(qv, (p >> 17) < cut, aA, aB);
            }
            if (l == 0) {
#pragma unroll
                for (int j = 0; j < 8; ++j) atomicAdd(&acc[gA * ACC_STRIDE + j], aA[j]);
            } else {
                atomicAdd(&acc[gA * ACC_STRIDE + 8], aA[0]);
                atomicAdd(&acc[gA * ACC_STRIDE + 9], aA[1]);
            }
            if (span == 1) {
                if (l == 0) {
#pragma unroll
                    for (int j = 0; j < 8; ++j) atomicAdd(&acc[gB * ACC_STRIDE + j], aB[j]);
                } else {
                    atomicAdd(&acc[gB * ACC_STRIDE + 8], aB[0]);
                    atomicAdd(&acc[gB * ACC_STRIDE + 9], aB[1]);
                }
            }
        } else {
            // generic (rare): per-edge graph via cut counting
            for (; e < c1; e += STR) {
                int p   = pk[e];
                int loc = p >> 17;
                float4 qv = r4[(size_t)(p & 0x1FFFF) * 2 + l];
                float2 u0 = __half22float2(__builtin_bit_cast(__half2, qv.x));
                float2 u1 = __half22float2(__builtin_bit_cast(__half2, qv.y));
                float2 u2 = __half22float2(__builtin_bit_cast(__half2, qv.z));
                float2 u3 = __half22float2(__builtin_bit_cast(__half2, qv.w));
                int g = glo;
                for (int gg = glo + 1; gg <= ghi; ++gg)
                    g += (loc >= bound[gg] - nbase) ? 1 : 0;
                if (l == 0) {
                    atomicAdd(&acc[g * ACC_STRIDE + 0], u0.x);
                    atomicAdd(&acc[g * ACC_STRIDE + 1], u0.y);
                    atomicAdd(&acc[g * ACC_STRIDE + 2], u1.x);
                    atomicAdd(&acc[g * ACC_STRIDE + 3], u1.y);
                    atomicAdd(&acc[g * ACC_STRIDE + 4], u2.x);
                    atomicAdd(&acc[g * ACC_STRIDE + 5], u2.y);
                    atomicAdd(&acc[g * ACC_STRIDE + 6], u3.x);
                    atomicAdd(&acc[g * ACC_STRIDE + 7], u3.y);
                } else {
                    atomicAdd(&acc[g * ACC_STRIDE + 8], u0.x);
                    atomicAdd(&acc[g * ACC_STRIDE + 9], u0.y);
                }
            }
        }
    }
    __syncthreads();

    for (int t = threadIdx.x; t < (span + 1) * DIM; t += 512) {
        int g = glo + t / DIM;
        float v = acc[g * ACC_STRIDE + t % DIM];
        if (v != 0.f) atomicAdd(&sums[g * DIM + t % DIM], v);
    }
}

// out[g] = sigmoid(((sums[g]/max(cnt,1)) @ W2) @ W3)
__global__ void k_final(const float* __restrict__ sums, const int* __restrict__ bound,
                        const float* __restrict__ W2, const float* __restrict__ W3,
                        float* __restrict__ out) {
    int g = threadIdx.x;
    if (g >= NUM_GRAPHS) return;
    float c = fmaxf((float)(bound[g + 1] - bound[g]), 1.f);
    float p[DIM];
#pragma unroll
    for (int k = 0; k < DIM; ++k) p[k] = sums[g * DIM + k] / c;
    float z = 0.f;
#pragma unroll
    for (int j = 0; j < DIM; ++j) {
        float t = 0.f;
#pragma unroll
        for (int k = 0; k < DIM; ++k) t += p[k] * W2[k * DIM + j];
        z += t * W3[j];
    }
    out[g] = 1.f / (1.f + expf(-z));
}

// ---------------------------------------------------------------------------
// Workspace (bytes):
//   h1     [0,         3200000)    100k x 32B padded rows (L2-resident)
//   pk     [3200000,  28824576)    391 buckets x 16384 slots x 4B
//   r      [28824576, 32024576)    100k x 32B padded rows (L2-resident)
//   part   [32024576, 48039936)    1564 x 2560 f32
//   cnt    [48039936, 48041500)    391 int   \  zeroed by one 4128B memset
//   sums   [48041504, 48044064)    640 f32   /
//   bound  [48044064, 48044324)    65 int
// ---------------------------------------------------------------------------
extern "C" void kernel_launch(void* const* d_in, const int* in_sizes, int n_in,
                              void* d_out, int out_size, void* d_ws, size_t ws_size,
                              hipStream_t stream) {
    const float* feat = (const float*)d_in[0];
    const float* W1   = (const float*)d_in[1];
    const float* W2   = (const float*)d_in[2];
    const float* W3   = (const float*)d_in[3];
    const int*   src  = (const int*)d_in[4];
    const int*   dst  = (const int*)d_in[5];
    const int*   gids = (const int*)d_in[6];
    float*       out  = (float*)d_out;

    char* ws = (char*)d_ws;
    __half* h1    = (__half*)(ws);
    int*    pk    = (int*)(ws + 3200000);
    __half* r     = (__half*)(ws + 28824576);
    float*  part  = (float*)(ws + 32024576);
    int*    cnt   = (int*)(ws + 48039936);
    float*  sums  = (float*)(ws + 48041504);
    int*    bound = (int*)(ws + 48044064);

    // zero cnt (391 int) + pad + sums (640 f32) in one tiny DMA
    hipMemsetAsync(ws + 48039936, 0, 4128, stream);

    k_front<<<PLACE_BLOCKS + GEMM_BLOCKS, 512, 0, stream>>>(feat, W1, h1, gids, bound,
                                                            src, dst, cnt, pk);
    k_spmm1     <<<NCHUNK, 512, 0, stream>>>(h1, cnt, pk, part);
    k_merge_relu<<<NB, 256, 0, stream>>>(part, r);
    k_pass2     <<<NCHUNK2, 512, 0, stream>>>(r, cnt, pk, bound, sums);

    k_final<<<1, 64, 0, stream>>>(sums, bound, W2, W3, out);
}

// Round 11
// 218.734 us; speedup vs baseline: 1.0352x; 1.0352x over previous
//
#include <hip/hip_runtime.h>
#include <hip/hip_fp16.h>

#define N_NODES 100000
#define N_EDGES 3200000
#define NUM_FEATURES 128
#define DIM 10
#define NUM_GRAPHS 64

#define BSHIFT 8                             // 256 nodes per bucket
#define BSIZE (1 << BSHIFT)
#define NB ((N_NODES + BSIZE - 1) / BSIZE)   // 391 buckets
#define CHUNKS 4                             // spmm1 chunks per bucket
#define PCHUNKS 4                            // pass2 chunks per bucket
#define EPB 12500                            // edges per placement block
#define PLACE_BLOCKS 256                     // 256 * 12500 = 3.2M exact
#define NQUAD 25000                          // 100k nodes / 4 per 32-lane group
#define GEMM_BLOCKS 1563                     // ceil(25000*32 / 512)
#define BOUND_BLOCKS 196                     // ceil(100000 / 512)
#define CAP 2560                             // max edges per spmm1 chunk (mean 2046, +22 sigma)
#define CAPB 16384                           // per-bucket pk region capacity (+90 sigma)
#define NCHUNK (NB * CHUNKS)                 // 1564
#define NCHUNK2 (NB * PCHUNKS)               // 1564
#define ACC_STRIDE 11

// f32 add of DPP row-rotated value (VALU pipe)
#define DPP_ROR_ADD(v, n)                                                        \
    (v) += __int_as_float(__builtin_amdgcn_update_dpp(                           \
        0, __float_as_int(v), 0x120 | (n), 0xF, 0xF, false))

// ---------------------------------------------------------------------------
// Fused front-end (R5-proven; best measured config, 206us total).
// Lessons ledger: R3 no cross-block fences (per-XCD L2 wb+inv = 3x). R4/R6 no
// extra place blocks / line-pad (HBM write-amp). R7 no k-indexed LDS W1 (bank
// conflicts). R8/R9 W1 is already loaded once/thread; k_front ~55us is
// intrinsic TA+VALU+tail. R10 no 32B-padded gather rows (2x bytes+VALU).
// ---------------------------------------------------------------------------
__global__ __launch_bounds__(512) void k_front(const float* __restrict__ feat,
                                               const float* __restrict__ W1,
                                               __half* __restrict__ h1,
                                               const int* __restrict__ gids,
                                               int* __restrict__ bound,
                                               const int* __restrict__ src,
                                               const int* __restrict__ dst,
                                               int* __restrict__ cnt,
                                               int* __restrict__ pk) {
    __shared__ int hd[NB];      // placement: per-block histogram
    __shared__ int cb[NB];      // placement: absolute write cursors

    if (blockIdx.x < PLACE_BLOCKS) {
        int base0 = blockIdx.x * EPB;
        for (int t = threadIdx.x; t < NB; t += 512) hd[t] = 0;
        __syncthreads();

        // phase 1: histogram (coalesced 4-batched dst loads)
        {
            int i = threadIdx.x;
            for (; i + 1536 < EPB; i += 2048) {
                int d0 = dst[base0 + i],        d1 = dst[base0 + i + 512];
                int d2 = dst[base0 + i + 1024], d3 = dst[base0 + i + 1536];
                atomicAdd(&hd[d0 >> BSHIFT], 1);
                atomicAdd(&hd[d1 >> BSHIFT], 1);
                atomicAdd(&hd[d2 >> BSHIFT], 1);
                atomicAdd(&hd[d3 >> BSHIFT], 1);
            }
            for (; i < EPB; i += 512)
                atomicAdd(&hd[dst[base0 + i] >> BSHIFT], 1);
        }
        __syncthreads();

        // phase 2: reserve contiguous range in bucket region via global atomic
        for (int t = threadIdx.x; t < NB; t += 512) {
            int c = hd[t];
            int o = c ? atomicAdd(&cnt[t], c) : 0;
            cb[t] = t * CAPB + o;
        }
        __syncthreads();

        // phase 3: place (dst re-read is L2-hot; 1 LDS atomic/edge; clamp=safety)
        {
            int i = threadIdx.x;
            for (; i + 1536 < EPB; i += 2048) {
                int d0 = dst[base0 + i],        d1 = dst[base0 + i + 512];
                int d2 = dst[base0 + i + 1024], d3 = dst[base0 + i + 1536];
                int s0 = src[base0 + i],        s1 = src[base0 + i + 512];
                int s2 = src[base0 + i + 1024], s3 = src[base0 + i + 1536];
                int q0 = atomicAdd(&cb[d0 >> BSHIFT], 1);
                int q1 = atomicAdd(&cb[d1 >> BSHIFT], 1);
                int q2 = atomicAdd(&cb[d2 >> BSHIFT], 1);
                int q3 = atomicAdd(&cb[d3 >> BSHIFT], 1);
                if (q0 < ((d0 >> BSHIFT) + 1) * CAPB) pk[q0] = ((d0 & (BSIZE - 1)) << 17) | s0;
                if (q1 < ((d1 >> BSHIFT) + 1) * CAPB) pk[q1] = ((d1 & (BSIZE - 1)) << 17) | s1;
                if (q2 < ((d2 >> BSHIFT) + 1) * CAPB) pk[q2] = ((d2 & (BSIZE - 1)) << 17) | s2;
                if (q3 < ((d3 >> BSHIFT) + 1) * CAPB) pk[q3] = ((d3 & (BSIZE - 1)) << 17) | s3;
            }
            for (; i < EPB; i += 512) {
                int d = dst[base0 + i];
                int s = src[base0 + i];
                int q = atomicAdd(&cb[d >> BSHIFT], 1);
                if (q < ((d >> BSHIFT) + 1) * CAPB) pk[q] = ((d & (BSIZE - 1)) << 17) | s;
            }
        }
        return;
    }

    // ---- GEMM half: 4 nodes per 32-lane group ----
    int bb = blockIdx.x - PLACE_BLOCKS;

    // fused graph-boundary computation (gids sorted)
    int nb2 = bb * 512 + threadIdx.x;
    if (bb < BOUND_BLOCKS && nb2 < N_NODES) {
        int g  = gids[nb2];
        int gp = nb2 ? gids[nb2 - 1] : -1;
        for (int v = gp + 1; v <= g; ++v) bound[v] = nb2;
        if (nb2 == N_NODES - 1)
            for (int v = g + 1; v <= NUM_GRAPHS; ++v) bound[v] = N_NODES;
    }

    int gid  = bb * 512 + threadIdx.x;
    int quad = gid >> 5;                 // node quad id
    int lane = gid & 31;
    if (quad >= NQUAD) return;

    // lane's W1 slice (rows lane*4..lane*4+3, 160B contiguous) as 10 dwordx4
    float wf[40];
    {
        const float4* W14 = reinterpret_cast<const float4*>(W1 + lane * 40);
#pragma unroll
        for (int m = 0; m < 10; ++m) {
            float4 q = W14[m];
            wf[4 * m]     = q.x;
            wf[4 * m + 1] = q.y;
            wf[4 * m + 2] = q.z;
            wf[4 * m + 3] = q.w;
        }
    }

    int nbase = quad * 4;
    float4 f[4];
#pragma unroll
    for (int n = 0; n < 4; ++n)
        f[n] = *reinterpret_cast<const float4*>(feat + (size_t)(nbase + n) * NUM_FEATURES + lane * 4);

    float acc[4][DIM];
#pragma unroll
    for (int n = 0; n < 4; ++n)
#pragma unroll
        for (int k = 0; k < DIM; ++k) acc[n][k] = 0.f;

#pragma unroll
    for (int n = 0; n < 4; ++n) {
        float fv[4] = {f[n].x, f[n].y, f[n].z, f[n].w};
#pragma unroll
        for (int j = 0; j < 4; ++j)
#pragma unroll
            for (int k = 0; k < DIM; ++k)
                acc[n][k] += fv[j] * wf[j * DIM + k];
    }

    // reduce over 32 lanes: 4 in-row DPP rotate-adds (VALU) + 1 shfl_xor(16)
#pragma unroll
    for (int n = 0; n < 4; ++n)
#pragma unroll
        for (int k = 0; k < DIM; ++k) {
            float v = acc[n][k];
            DPP_ROR_ADD(v, 1);
            DPP_ROR_ADD(v, 2);
            DPP_ROR_ADD(v, 4);
            DPP_ROR_ADD(v, 8);
            acc[n][k] = v + __shfl_xor(v, 16);
        }

    if (lane == 0) {
        __half2* o = (__half2*)h1;
#pragma unroll
        for (int n = 0; n < 4; ++n)
#pragma unroll
            for (int j = 0; j < 5; ++j)
                o[(size_t)(nbase + n) * 5 + j] = __floats2half2_rn(acc[n][2 * j], acc[n][2 * j + 1]);
    }
}

// ---------------------------------------------------------------------------
// Pass 1 SpMM (R9 sort structure). Gather accumulates in registers, then
// flushes via direct f32 atomicAdd into rf32 (zeroed) — replaces the part
// buffer + k_merge_relu kernel (32MB HBM round-trip + one launch). Atomics
// are uncontended (<=CHUNKS writers/address); no fences needed (R3 lesson:
// fences, not atomics, were the poison).
// ---------------------------------------------------------------------------
__global__ __launch_bounds__(512) void k_spmm1(const __half* __restrict__ h,
                                               const int* __restrict__ cnt,
                                               const int* __restrict__ pk,
                                               float* __restrict__ rf32) {
    __shared__ int eh[CAP];
    __shared__ int srt[CAP];
    __shared__ int hist[BSIZE];
    __shared__ int cur[BSIZE];

    int b     = blockIdx.x / CHUNKS;
    int chunk = blockIdx.x % CHUNKS;
    int s0  = b * CAPB;
    int len = cnt[b];
    int c0  = s0 + (len * chunk) / CHUNKS;
    int c1  = s0 + (len * (chunk + 1)) / CHUNKS;
    int n   = c1 - c0;
    int nc  = min(n, CAP);

    for (int t = threadIdx.x; t < BSIZE; t += 512) hist[t] = 0;
    __syncthreads();

    {
        int i = threadIdx.x;
        for (; i + 1536 < nc; i += 2048) {
            int p0 = pk[c0 + i],        p1 = pk[c0 + i + 512];
            int p2 = pk[c0 + i + 1024], p3 = pk[c0 + i + 1536];
            eh[i] = p0; eh[i + 512] = p1; eh[i + 1024] = p2; eh[i + 1536] = p3;
            atomicAdd(&hist[p0 >> 17], 1);
            atomicAdd(&hist[p1 >> 17], 1);
            atomicAdd(&hist[p2 >> 17], 1);
            atomicAdd(&hist[p3 >> 17], 1);
        }
        for (; i < nc; i += 512) {
            int p = pk[c0 + i];
            eh[i] = p;
            atomicAdd(&hist[p >> 17], 1);
        }
    }
    __syncthreads();

    if (threadIdx.x < 64) {
        int l = threadIdx.x;
        int carry = 0;
#pragma unroll
        for (int j = 0; j < 4; ++j) {
            int x = hist[j * 64 + l];
            int v = x;
#pragma unroll
            for (int off = 1; off < 64; off <<= 1) {
                int t2 = __shfl_up(v, off);
                if (l >= off) v += t2;
            }
            cur[j * 64 + l] = carry + v - x;
            carry += __shfl(v, 63);
        }
    }
    __syncthreads();

    for (int i = threadIdx.x; i < nc; i += 512) {
        int p = eh[i];
        int pos = atomicAdd(&cur[p >> 17], 1);
        srt[pos] = p;
    }
    __syncthreads();

    int wave = threadIdx.x >> 6;
    int lane = threadIdx.x & 63;
    int slot = lane / 5;            // 0..12 (12 = idle lanes 60..63)
    int l    = lane - slot * 5;     // half2 index within the row
    const __half2* h2 = (const __half2*)h;

    if (slot < 12) {
        int g = wave * 12 + slot;   // 0..95
        for (int loc = g; loc < BSIZE; loc += 96) {
            int e0 = loc ? cur[loc - 1] : 0;
            int e1 = cur[loc];
            if (e1 <= e0) continue;                   // nothing to add
            float ax0 = 0.f, ay0 = 0.f, ax1 = 0.f, ay1 = 0.f;
            float ax2 = 0.f, ay2 = 0.f, ax3 = 0.f, ay3 = 0.f;
            int e = e0;
            for (; e + 7 < e1; e += 8) {
                float2 v0 = __half22float2(h2[(size_t)(srt[e]     & 0x1FFFF) * 5 + l]);
                float2 v1 = __half22float2(h2[(size_t)(srt[e + 1] & 0x1FFFF) * 5 + l]);
                float2 v2 = __half22float2(h2[(size_t)(srt[e + 2] & 0x1FFFF) * 5 + l]);
                float2 v3 = __half22float2(h2[(size_t)(srt[e + 3] & 0x1FFFF) * 5 + l]);
                float2 v4 = __half22float2(h2[(size_t)(srt[e + 4] & 0x1FFFF) * 5 + l]);
                float2 v5 = __half22float2(h2[(size_t)(srt[e + 5] & 0x1FFFF) * 5 + l]);
                float2 v6 = __half22float2(h2[(size_t)(srt[e + 6] & 0x1FFFF) * 5 + l]);
                float2 v7 = __half22float2(h2[(size_t)(srt[e + 7] & 0x1FFFF) * 5 + l]);
                ax0 += v0.x + v4.x; ay0 += v0.y + v4.y;
                ax1 += v1.x + v5.x; ay1 += v1.y + v5.y;
                ax2 += v2.x + v6.x; ay2 += v2.y + v6.y;
                ax3 += v3.x + v7.x; ay3 += v3.y + v7.y;
            }
            for (; e < e1; ++e) {
                float2 v = __half22float2(h2[(size_t)(srt[e] & 0x1FFFF) * 5 + l]);
                ax0 += v.x; ay0 += v.y;
            }
            int node = (b << BSHIFT) + loc;           // valid: loc came from real dst
            atomicAdd(&rf32[(size_t)node * DIM + 2 * l],     (ax0 + ax1) + (ax2 + ax3));
            atomicAdd(&rf32[(size_t)node * DIM + 2 * l + 1], (ay0 + ay1) + (ay2 + ay3));
        }
    }
    __syncthreads();

    // overflow fallback (statistically never; correctness guard)
    for (int i = CAP + threadIdx.x; i < n; i += 512) {
        int p = pk[c0 + i];
        int loc = p >> 17, s = p & 0x1FFFF;
        int node = (b << BSHIFT) + loc;
#pragma unroll
        for (int j = 0; j < 5; ++j) {
            float2 v = __half22float2(h2[(size_t)s * 5 + j]);
            atomicAdd(&rf32[(size_t)node * DIM + 2 * j], v.x);
            atomicAdd(&rf32[(size_t)node * DIM + 2 * j + 1], v.y);
        }
    }
}

// ---------------------------------------------------------------------------
// Pass 2 (R9 structure): gathers rf32 with relu applied on load (merge kernel
// deleted). Bucket spans <=1 graph boundary in ~all cases: branchless dual
// accumulator, 8-deep batched pk->rf32 loads, global-atomic flush.
// ---------------------------------------------------------------------------
__global__ __launch_bounds__(512) void k_pass2(const float* __restrict__ rf32,
                                               const int* __restrict__ cnt,
                                               const int* __restrict__ pk,
                                               const int* __restrict__ bound,
                                               float* __restrict__ sums) {
    __shared__ float acc[NUM_GRAPHS * ACC_STRIDE];

    int b     = blockIdx.x / PCHUNKS;
    int chunk = blockIdx.x % PCHUNKS;
    int nbase = b << BSHIFT;
    int nlast = min(nbase + BSIZE - 1, N_NODES - 1);

    int glo = 0, ghx = NUM_GRAPHS - 1;
#pragma unroll
    for (int it = 0; it < 6; ++it) {
        int mid = (glo + ghx + 1) >> 1;
        if (bound[mid] <= nbase) glo = mid; else ghx = mid - 1;
    }
    int lo2 = 0, hi2 = NUM_GRAPHS - 1;
#pragma unroll
    for (int it = 0; it < 6; ++it) {
        int mid = (lo2 + hi2 + 1) >> 1;
        if (bound[mid] <= nlast) lo2 = mid; else hi2 = mid - 1;
    }
    int ghi  = lo2;
    int span = ghi - glo;

    for (int t = threadIdx.x; t < (span + 1) * DIM; t += 512)
        acc[(glo + t / DIM) * ACC_STRIDE + t % DIM] = 0.f;
    __syncthreads();

    int s0  = b * CAPB;
    int len = cnt[b];
    int c0  = s0 + (len * chunk) / PCHUNKS;
    int c1  = s0 + (len * (chunk + 1)) / PCHUNKS;

    int wave = threadIdx.x >> 6;
    int lane = threadIdx.x & 63;
    int slot = lane / 5;
    int l    = lane - slot * 5;
    const float2* r2 = (const float2*)rf32;

    if (slot < 12) {
        const int STR = 96;
        int q = wave * 12 + slot;
        int e = c0 + q;
        if (span <= 1) {
            int gA  = glo;
            int gB  = (span == 1) ? glo + 1 : glo;
            int cut = (span == 1) ? (bound[glo + 1] - nbase) : BSIZE;
            float axA = 0.f, ayA = 0.f, axB = 0.f, ayB = 0.f;
            for (; e + 7 * STR < c1; e += 8 * STR) {
                int p[8];
#pragma unroll
                for (int u = 0; u < 8; ++u) p[u] = pk[e + u * STR];
                float2 v[8];
#pragma unroll
                for (int u = 0; u < 8; ++u) {
                    v[u] = r2[(size_t)(p[u] & 0x1FFFF) * 5 + l];
                    v[u].x = fmaxf(v[u].x, 0.f);
                    v[u].y = fmaxf(v[u].y, 0.f);
                }
#pragma unroll
                for (int u = 0; u < 8; ++u) {
                    bool a = (p[u] >> 17) < cut;
                    axA += a ? v[u].x : 0.f;  ayA += a ? v[u].y : 0.f;
                    axB += a ? 0.f : v[u].x;  ayB += a ? 0.f : v[u].y;
                }
            }
            for (; e < c1; e += STR) {
                int p = pk[e];
                float2 v = r2[(size_t)(p & 0x1FFFF) * 5 + l];
                v.x = fmaxf(v.x, 0.f);
                v.y = fmaxf(v.y, 0.f);
                bool a = (p >> 17) < cut;
                axA += a ? v.x : 0.f;  ayA += a ? v.y : 0.f;
                axB += a ? 0.f : v.x;  ayB += a ? 0.f : v.y;
            }
            atomicAdd(&acc[gA * ACC_STRIDE + 2 * l], axA);
            atomicAdd(&acc[gA * ACC_STRIDE + 2 * l + 1], ayA);
            if (span == 1) {
                atomicAdd(&acc[gB * ACC_STRIDE + 2 * l], axB);
                atomicAdd(&acc[gB * ACC_STRIDE + 2 * l + 1], ayB);
            }
        } else {
            for (; e < c1; e += STR) {
                int p   = pk[e];
                int loc = p >> 17;
                float2 v = r2[(size_t)(p & 0x1FFFF) * 5 + l];
                v.x = fmaxf(v.x, 0.f);
                v.y = fmaxf(v.y, 0.f);
                int g = glo;
                for (int gg = glo + 1; gg <= ghi; ++gg)
                    g += (loc >= bound[gg] - nbase) ? 1 : 0;
                atomicAdd(&acc[g * ACC_STRIDE + 2 * l], v.x);
                atomicAdd(&acc[g * ACC_STRIDE + 2 * l + 1], v.y);
            }
        }
    }
    __syncthreads();

    for (int t = threadIdx.x; t < (span + 1) * DIM; t += 512) {
        int g = glo + t / DIM;
        float v = acc[g * ACC_STRIDE + t % DIM];
        if (v != 0.f) atomicAdd(&sums[g * DIM + t % DIM], v);
    }
}

// out[g] = sigmoid(((sums[g]/max(cnt,1)) @ W2) @ W3)
__global__ void k_final(const float* __restrict__ sums, const int* __restrict__ bound,
                        const float* __restrict__ W2, const float* __restrict__ W3,
                        float* __restrict__ out) {
    int g = threadIdx.x;
    if (g >= NUM_GRAPHS) return;
    float c = fmaxf((float)(bound[g + 1] - bound[g]), 1.f);
    float p[DIM];
#pragma unroll
    for (int k = 0; k < DIM; ++k) p[k] = sums[g * DIM + k] / c;
    float z = 0.f;
#pragma unroll
    for (int j = 0; j < DIM; ++j) {
        float t = 0.f;
#pragma unroll
        for (int k = 0; k < DIM; ++k) t += p[k] * W2[k * DIM + j];
        z += t * W3[j];
    }
    out[g] = 1.f / (1.f + expf(-z));
}

// ---------------------------------------------------------------------------
// Workspace (bytes):
//   h1     [0,         2000000)    100k x 10 fp16 (L2-resident)
//   pk     [2000000,  27624576)    391 buckets x 16384 slots x 4B
//   rf32   [27624576, 31624576)    100k x 10 f32 pre-relu aggregate  \
//   cnt    [31624576, 31626140)    391 int                            | one
//   (pad)  [31626140, 31626144)                                       | memset
//   sums   [31626144, 31628704)    640 f32                           /
//   bound  [31628704, 31628964)    65 int
// ---------------------------------------------------------------------------
extern "C" void kernel_launch(void* const* d_in, const int* in_sizes, int n_in,
                              void* d_out, int out_size, void* d_ws, size_t ws_size,
                              hipStream_t stream) {
    const float* feat = (const float*)d_in[0];
    const float* W1   = (const float*)d_in[1];
    const float* W2   = (const float*)d_in[2];
    const float* W3   = (const float*)d_in[3];
    const int*   src  = (const int*)d_in[4];
    const int*   dst  = (const int*)d_in[5];
    const int*   gids = (const int*)d_in[6];
    float*       out  = (float*)d_out;

    char* ws = (char*)d_ws;
    __half* h1    = (__half*)(ws);
    int*    pk    = (int*)(ws + 2000000);
    float*  rf32  = (float*)(ws + 27624576);
    int*    cnt   = (int*)(ws + 31624576);
    float*  sums  = (float*)(ws + 31626144);
    int*    bound = (int*)(ws + 31628704);

    // zero rf32 (4MB) + cnt + sums in one DMA (~0.7us)
    hipMemsetAsync(ws + 27624576, 0, 4004128, stream);

    k_front<<<PLACE_BLOCKS + GEMM_BLOCKS, 512, 0, stream>>>(feat, W1, h1, gids, bound,
                                                            src, dst, cnt, pk);
    k_spmm1<<<NCHUNK, 512, 0, stream>>>(h1, cnt, pk, rf32);
    k_pass2<<<NCHUNK2, 512, 0, stream>>>(rf32, cnt, pk, bound, sums);

    k_final<<<1, 64, 0, stream>>>(sums, bound, W2, W3, out);
}

// Round 12
// 205.164 us; speedup vs baseline: 1.1037x; 1.0661x over previous
//
#include <hip/hip_runtime.h>
#include <hip/hip_fp16.h>

#define N_NODES 100000
#define N_EDGES 3200000
#define NUM_FEATURES 128
#define DIM 10
#define NUM_GRAPHS 64

#define BSHIFT 8                             // 256 nodes per bucket
#define BSIZE (1 << BSHIFT)
#define NB ((N_NODES + BSIZE - 1) / BSIZE)   // 391 buckets
#define CHUNKS 4                             // spmm1 chunks per bucket
#define PCHUNKS 4                            // pass2 chunks per bucket
#define EPB 6250                             // edges per placement block
#define PLACE_BLOCKS 512                     // 512 * 6250 = 3.2M exact (R12: isolated A/B vs 256)
#define NQUAD 25000                          // 100k nodes / 4 per 32-lane group
#define GEMM_BLOCKS 1563                     // ceil(25000*32 / 512)
#define BOUND_BLOCKS 196                     // ceil(100000 / 512)
#define TILE (BSIZE * DIM)                   // 2560 floats per bucket part tile
#define CAP 2560                             // max edges per spmm1 chunk (mean 2046, +22 sigma)
#define CAPB 16384                           // per-bucket pk region capacity (+90 sigma)
#define NCHUNK (NB * CHUNKS)                 // 1564
#define NCHUNK2 (NB * PCHUNKS)               // 1564
#define ACC_STRIDE 11

// f32 add of DPP row-rotated value (VALU pipe)
#define DPP_ROR_ADD(v, n)                                                        \
    (v) += __int_as_float(__builtin_amdgcn_update_dpp(                           \
        0, __float_as_int(v), 0x120 | (n), 0xF, 0xF, false))

// ---------------------------------------------------------------------------
// Fused front-end. R12 change (single variable vs the 206us R8/R9 config):
// PLACE_BLOCKS 256->512. Counters showed the placement tail (256 blocks,
// 1/CU) running alone ~40us at 0.5-1 TB/s after GEMM blocks drain; 512
// blocks halves the tail at a measured-bounded write-amp cost (~+14MB).
// Lessons ledger: R3 no cross-block fences (per-XCD L2 wb+inv = 3x). R6 no
// pk line-padding. R7 no k-indexed LDS W1 (bank conflicts 8.6x). R8/R9 W1 is
// loaded once/thread already. R10 no 32B padded gather rows. R11 no f32
// gather table (4MB breaks per-XCD L2 residency of the pass2 gather).
// ---------------------------------------------------------------------------
__global__ __launch_bounds__(512) void k_front(const float* __restrict__ feat,
                                               const float* __restrict__ W1,
                                               __half* __restrict__ h1,
                                               const int* __restrict__ gids,
                                               int* __restrict__ bound,
                                               const int* __restrict__ src,
                                               const int* __restrict__ dst,
                                               int* __restrict__ cnt,
                                               int* __restrict__ pk) {
    __shared__ int hd[NB];      // placement: per-block histogram
    __shared__ int cb[NB];      // placement: absolute write cursors

    if (blockIdx.x < PLACE_BLOCKS) {
        int base0 = blockIdx.x * EPB;
        for (int t = threadIdx.x; t < NB; t += 512) hd[t] = 0;
        __syncthreads();

        // phase 1: histogram (coalesced 4-batched dst loads)
        {
            int i = threadIdx.x;
            for (; i + 1536 < EPB; i += 2048) {
                int d0 = dst[base0 + i],        d1 = dst[base0 + i + 512];
                int d2 = dst[base0 + i + 1024], d3 = dst[base0 + i + 1536];
                atomicAdd(&hd[d0 >> BSHIFT], 1);
                atomicAdd(&hd[d1 >> BSHIFT], 1);
                atomicAdd(&hd[d2 >> BSHIFT], 1);
                atomicAdd(&hd[d3 >> BSHIFT], 1);
            }
            for (; i < EPB; i += 512)
                atomicAdd(&hd[dst[base0 + i] >> BSHIFT], 1);
        }
        __syncthreads();

        // phase 2: reserve contiguous range in bucket region via global atomic
        for (int t = threadIdx.x; t < NB; t += 512) {
            int c = hd[t];
            int o = c ? atomicAdd(&cnt[t], c) : 0;
            cb[t] = t * CAPB + o;
        }
        __syncthreads();

        // phase 3: place (dst re-read is L2-hot; 1 LDS atomic/edge; clamp=safety)
        {
            int i = threadIdx.x;
            for (; i + 1536 < EPB; i += 2048) {
                int d0 = dst[base0 + i],        d1 = dst[base0 + i + 512];
                int d2 = dst[base0 + i + 1024], d3 = dst[base0 + i + 1536];
                int s0 = src[base0 + i],        s1 = src[base0 + i + 512];
                int s2 = src[base0 + i + 1024], s3 = src[base0 + i + 1536];
                int q0 = atomicAdd(&cb[d0 >> BSHIFT], 1);
                int q1 = atomicAdd(&cb[d1 >> BSHIFT], 1);
                int q2 = atomicAdd(&cb[d2 >> BSHIFT], 1);
                int q3 = atomicAdd(&cb[d3 >> BSHIFT], 1);
                if (q0 < ((d0 >> BSHIFT) + 1) * CAPB) pk[q0] = ((d0 & (BSIZE - 1)) << 17) | s0;
                if (q1 < ((d1 >> BSHIFT) + 1) * CAPB) pk[q1] = ((d1 & (BSIZE - 1)) << 17) | s1;
                if (q2 < ((d2 >> BSHIFT) + 1) * CAPB) pk[q2] = ((d2 & (BSIZE - 1)) << 17) | s2;
                if (q3 < ((d3 >> BSHIFT) + 1) * CAPB) pk[q3] = ((d3 & (BSIZE - 1)) << 17) | s3;
            }
            for (; i < EPB; i += 512) {
                int d = dst[base0 + i];
                int s = src[base0 + i];
                int q = atomicAdd(&cb[d >> BSHIFT], 1);
                if (q < ((d >> BSHIFT) + 1) * CAPB) pk[q] = ((d & (BSIZE - 1)) << 17) | s;
            }
        }
        return;
    }

    // ---- GEMM half: 4 nodes per 32-lane group ----
    int bb = blockIdx.x - PLACE_BLOCKS;

    // fused graph-boundary computation (gids sorted)
    int nb2 = bb * 512 + threadIdx.x;
    if (bb < BOUND_BLOCKS && nb2 < N_NODES) {
        int g  = gids[nb2];
        int gp = nb2 ? gids[nb2 - 1] : -1;
        for (int v = gp + 1; v <= g; ++v) bound[v] = nb2;
        if (nb2 == N_NODES - 1)
            for (int v = g + 1; v <= NUM_GRAPHS; ++v) bound[v] = N_NODES;
    }

    int gid  = bb * 512 + threadIdx.x;
    int quad = gid >> 5;                 // node quad id
    int lane = gid & 31;
    if (quad >= NQUAD) return;

    // lane's W1 slice (rows lane*4..lane*4+3, 160B contiguous) as 10 dwordx4
    float wf[40];
    {
        const float4* W14 = reinterpret_cast<const float4*>(W1 + lane * 40);
#pragma unroll
        for (int m = 0; m < 10; ++m) {
            float4 q = W14[m];
            wf[4 * m]     = q.x;
            wf[4 * m + 1] = q.y;
            wf[4 * m + 2] = q.z;
            wf[4 * m + 3] = q.w;
        }
    }

    int nbase = quad * 4;
    float4 f[4];
#pragma unroll
    for (int n = 0; n < 4; ++n)
        f[n] = *reinterpret_cast<const float4*>(feat + (size_t)(nbase + n) * NUM_FEATURES + lane * 4);

    float acc[4][DIM];
#pragma unroll
    for (int n = 0; n < 4; ++n)
#pragma unroll
        for (int k = 0; k < DIM; ++k) acc[n][k] = 0.f;

#pragma unroll
    for (int n = 0; n < 4; ++n) {
        float fv[4] = {f[n].x, f[n].y, f[n].z, f[n].w};
#pragma unroll
        for (int j = 0; j < 4; ++j)
#pragma unroll
            for (int k = 0; k < DIM; ++k)
                acc[n][k] += fv[j] * wf[j * DIM + k];
    }

    // reduce over 32 lanes: 4 in-row DPP rotate-adds (VALU) + 1 shfl_xor(16)
#pragma unroll
    for (int n = 0; n < 4; ++n)
#pragma unroll
        for (int k = 0; k < DIM; ++k) {
            float v = acc[n][k];
            DPP_ROR_ADD(v, 1);
            DPP_ROR_ADD(v, 2);
            DPP_ROR_ADD(v, 4);
            DPP_ROR_ADD(v, 8);
            acc[n][k] = v + __shfl_xor(v, 16);
        }

    if (lane == 0) {
        __half2* o = (__half2*)h1;
#pragma unroll
        for (int n = 0; n < 4; ++n)
#pragma unroll
            for (int j = 0; j < 5; ++j)
                o[(size_t)(nbase + n) * 5 + j] = __floats2half2_rn(acc[n][2 * j], acc[n][2 * j + 1]);
    }
}

// ---------------------------------------------------------------------------
// Pass 1 SpMM (R8/R9-proven, CHUNKS=4): in-block counting sort to exact
// dst-loc (eh stash, 2 LDS atomics/edge, 4-batched pk loads), exclusive-owner
// segmented gather (12 slots x 5 lanes, 8-deep), register acc, non-atomic
// writes.
// ---------------------------------------------------------------------------
__global__ __launch_bounds__(512) void k_spmm1(const __half* __restrict__ h,
                                               const int* __restrict__ cnt,
                                               const int* __restrict__ pk,
                                               float* __restrict__ part) {
    __shared__ int eh[CAP];
    __shared__ int srt[CAP];
    __shared__ int hist[BSIZE];
    __shared__ int cur[BSIZE];

    int b     = blockIdx.x / CHUNKS;
    int chunk = blockIdx.x % CHUNKS;
    int s0  = b * CAPB;
    int len = cnt[b];
    int c0  = s0 + (len * chunk) / CHUNKS;
    int c1  = s0 + (len * (chunk + 1)) / CHUNKS;
    int n   = c1 - c0;
    int nc  = min(n, CAP);

    for (int t = threadIdx.x; t < BSIZE; t += 512) hist[t] = 0;
    __syncthreads();

    {
        int i = threadIdx.x;
        for (; i + 1536 < nc; i += 2048) {
            int p0 = pk[c0 + i],        p1 = pk[c0 + i + 512];
            int p2 = pk[c0 + i + 1024], p3 = pk[c0 + i + 1536];
            eh[i] = p0; eh[i + 512] = p1; eh[i + 1024] = p2; eh[i + 1536] = p3;
            atomicAdd(&hist[p0 >> 17], 1);
            atomicAdd(&hist[p1 >> 17], 1);
            atomicAdd(&hist[p2 >> 17], 1);
            atomicAdd(&hist[p3 >> 17], 1);
        }
        for (; i < nc; i += 512) {
            int p = pk[c0 + i];
            eh[i] = p;
            atomicAdd(&hist[p >> 17], 1);
        }
    }
    __syncthreads();

    if (threadIdx.x < 64) {
        int l = threadIdx.x;
        int carry = 0;
#pragma unroll
        for (int j = 0; j < 4; ++j) {
            int x = hist[j * 64 + l];
            int v = x;
#pragma unroll
            for (int off = 1; off < 64; off <<= 1) {
                int t2 = __shfl_up(v, off);
                if (l >= off) v += t2;
            }
            cur[j * 64 + l] = carry + v - x;
            carry += __shfl(v, 63);
        }
    }
    __syncthreads();

    for (int i = threadIdx.x; i < nc; i += 512) {
        int p = eh[i];
        int pos = atomicAdd(&cur[p >> 17], 1);
        srt[pos] = p;
    }
    __syncthreads();

    int wave = threadIdx.x >> 6;
    int lane = threadIdx.x & 63;
    int slot = lane / 5;            // 0..12 (12 = idle lanes 60..63)
    int l    = lane - slot * 5;     // half2 index within the row
    float* pb = part + (size_t)blockIdx.x * TILE;
    const __half2* h2 = (const __half2*)h;

    if (slot < 12) {
        int g = wave * 12 + slot;   // 0..95
        for (int loc = g; loc < BSIZE; loc += 96) {
            int e0 = loc ? cur[loc - 1] : 0;
            int e1 = cur[loc];
            float ax0 = 0.f, ay0 = 0.f, ax1 = 0.f, ay1 = 0.f;
            float ax2 = 0.f, ay2 = 0.f, ax3 = 0.f, ay3 = 0.f;
            int e = e0;
            for (; e + 7 < e1; e += 8) {
                float2 v0 = __half22float2(h2[(size_t)(srt[e]     & 0x1FFFF) * 5 + l]);
                float2 v1 = __half22float2(h2[(size_t)(srt[e + 1] & 0x1FFFF) * 5 + l]);
                float2 v2 = __half22float2(h2[(size_t)(srt[e + 2] & 0x1FFFF) * 5 + l]);
                float2 v3 = __half22float2(h2[(size_t)(srt[e + 3] & 0x1FFFF) * 5 + l]);
                float2 v4 = __half22float2(h2[(size_t)(srt[e + 4] & 0x1FFFF) * 5 + l]);
                float2 v5 = __half22float2(h2[(size_t)(srt[e + 5] & 0x1FFFF) * 5 + l]);
                float2 v6 = __half22float2(h2[(size_t)(srt[e + 6] & 0x1FFFF) * 5 + l]);
                float2 v7 = __half22float2(h2[(size_t)(srt[e + 7] & 0x1FFFF) * 5 + l]);
                ax0 += v0.x + v4.x; ay0 += v0.y + v4.y;
                ax1 += v1.x + v5.x; ay1 += v1.y + v5.y;
                ax2 += v2.x + v6.x; ay2 += v2.y + v6.y;
                ax3 += v3.x + v7.x; ay3 += v3.y + v7.y;
            }
            for (; e < e1; ++e) {
                float2 v = __half22float2(h2[(size_t)(srt[e] & 0x1FFFF) * 5 + l]);
                ax0 += v.x; ay0 += v.y;
            }
            pb[loc * DIM + 2 * l]     = (ax0 + ax1) + (ax2 + ax3);
            pb[loc * DIM + 2 * l + 1] = (ay0 + ay1) + (ay2 + ay3);
        }
    }
    __syncthreads();

    // overflow fallback (statistically never; correctness guard)
    for (int i = CAP + threadIdx.x; i < n; i += 512) {
        int p = pk[c0 + i];
        int loc = p >> 17, s = p & 0x1FFFF;
#pragma unroll
        for (int j = 0; j < 5; ++j) {
            float2 v = __half22float2(h2[(size_t)s * 5 + j]);
            atomicAdd(&pb[loc * DIM + 2 * j], v.x);
            atomicAdd(&pb[loc * DIM + 2 * j + 1], v.y);
        }
    }
}

// merge CHUNKS partials + fused relu -> r (fp16, compact stride 10)
__global__ __launch_bounds__(256) void k_merge_relu(const float* __restrict__ part,
                                                    __half* __restrict__ r) {
    int b     = blockIdx.x;
    int nbase = b << BSHIFT;
    const float* p0 = part + (size_t)(b * CHUNKS) * TILE;
    __half2* r2 = (__half2*)r;
    for (int t = threadIdx.x; t < TILE / 2; t += 256) {
        float sx = 0.f, sy = 0.f;
#pragma unroll
        for (int c = 0; c < CHUNKS; ++c) {
            float2 v = ((const float2*)(p0 + (size_t)c * TILE))[t];
            sx += v.x; sy += v.y;
        }
        int ebase = nbase * DIM + 2 * t;
        if (ebase < N_NODES * DIM)
            r2[(size_t)nbase * 5 + t] = __floats2half2_rn(fmaxf(sx, 0.f), fmaxf(sy, 0.f));
    }
}

// ---------------------------------------------------------------------------
// Pass 2 (R8/R9-proven): bucket spans <=1 graph boundary in ~all cases.
// Branchless dual accumulator, 8-deep batched pk->r loads, global-atomic
// flush of <=2 graph rows.
// ---------------------------------------------------------------------------
__global__ __launch_bounds__(512) void k_pass2(const __half* __restrict__ r,
                                               const int* __restrict__ cnt,
                                               const int* __restrict__ pk,
                                               const int* __restrict__ bound,
                                               float* __restrict__ sums) {
    __shared__ float acc[NUM_GRAPHS * ACC_STRIDE];

    int b     = blockIdx.x / PCHUNKS;
    int chunk = blockIdx.x % PCHUNKS;
    int nbase = b << BSHIFT;
    int nlast = min(nbase + BSIZE - 1, N_NODES - 1);

    int glo = 0, ghx = NUM_GRAPHS - 1;
#pragma unroll
    for (int it = 0; it < 6; ++it) {
        int mid = (glo + ghx + 1) >> 1;
        if (bound[mid] <= nbase) glo = mid; else ghx = mid - 1;
    }
    int lo2 = 0, hi2 = NUM_GRAPHS - 1;
#pragma unroll
    for (int it = 0; it < 6; ++it) {
        int mid = (lo2 + hi2 + 1) >> 1;
        if (bound[mid] <= nlast) lo2 = mid; else hi2 = mid - 1;
    }
    int ghi  = lo2;
    int span = ghi - glo;

    for (int t = threadIdx.x; t < (span + 1) * DIM; t += 512)
        acc[(glo + t / DIM) * ACC_STRIDE + t % DIM] = 0.f;
    __syncthreads();

    int s0  = b * CAPB;
    int len = cnt[b];
    int c0  = s0 + (len * chunk) / PCHUNKS;
    int c1  = s0 + (len * (chunk + 1)) / PCHUNKS;

    int wave = threadIdx.x >> 6;
    int lane = threadIdx.x & 63;
    int slot = lane / 5;
    int l    = lane - slot * 5;
    const __half2* r2 = (const __half2*)r;

    if (slot < 12) {
        const int STR = 96;
        int q = wave * 12 + slot;
        int e = c0 + q;
        if (span <= 1) {
            int gA  = glo;
            int gB  = (span == 1) ? glo + 1 : glo;
            int cut = (span == 1) ? (bound[glo + 1] - nbase) : BSIZE;
            float axA = 0.f, ayA = 0.f, axB = 0.f, ayB = 0.f;
            for (; e + 7 * STR < c1; e += 8 * STR) {
                int p[8];
#pragma unroll
                for (int u = 0; u < 8; ++u) p[u] = pk[e + u * STR];
                float2 v[8];
#pragma unroll
                for (int u = 0; u < 8; ++u)
                    v[u] = __half22float2(r2[(size_t)(p[u] & 0x1FFFF) * 5 + l]);
#pragma unroll
                for (int u = 0; u < 8; ++u) {
                    bool a = (p[u] >> 17) < cut;
                    axA += a ? v[u].x : 0.f;  ayA += a ? v[u].y : 0.f;
                    axB += a ? 0.f : v[u].x;  ayB += a ? 0.f : v[u].y;
                }
            }
            for (; e < c1; e += STR) {
                int p = pk[e];
                float2 v = __half22float2(r2[(size_t)(p & 0x1FFFF) * 5 + l]);
                bool a = (p >> 17) < cut;
                axA += a ? v.x : 0.f;  ayA += a ? v.y : 0.f;
                axB += a ? 0.f : v.x;  ayB += a ? 0.f : v.y;
            }
            atomicAdd(&acc[gA * ACC_STRIDE + 2 * l], axA);
            atomicAdd(&acc[gA * ACC_STRIDE + 2 * l + 1], ayA);
            if (span == 1) {
                atomicAdd(&acc[gB * ACC_STRIDE + 2 * l], axB);
                atomicAdd(&acc[gB * ACC_STRIDE + 2 * l + 1], ayB);
            }
        } else {
            for (; e < c1; e += STR) {
                int p   = pk[e];
                int loc = p >> 17;
                float2 v = __half22float2(r2[(size_t)(p & 0x1FFFF) * 5 + l]);
                int g = glo;
                for (int gg = glo + 1; gg <= ghi; ++gg)
                    g += (loc >= bound[gg] - nbase) ? 1 : 0;
                atomicAdd(&acc[g * ACC_STRIDE + 2 * l], v.x);
                atomicAdd(&acc[g * ACC_STRIDE + 2 * l + 1], v.y);
            }
        }
    }
    __syncthreads();

    for (int t = threadIdx.x; t < (span + 1) * DIM; t += 512) {
        int g = glo + t / DIM;
        float v = acc[g * ACC_STRIDE + t % DIM];
        if (v != 0.f) atomicAdd(&sums[g * DIM + t % DIM], v);
    }
}

// out[g] = sigmoid(((sums[g]/max(cnt,1)) @ W2) @ W3)
__global__ void k_final(const float* __restrict__ sums, const int* __restrict__ bound,
                        const float* __restrict__ W2, const float* __restrict__ W3,
                        float* __restrict__ out) {
    int g = threadIdx.x;
    if (g >= NUM_GRAPHS) return;
    float c = fmaxf((float)(bound[g + 1] - bound[g]), 1.f);
    float p[DIM];
#pragma unroll
    for (int k = 0; k < DIM; ++k) p[k] = sums[g * DIM + k] / c;
    float z = 0.f;
#pragma unroll
    for (int j = 0; j < DIM; ++j) {
        float t = 0.f;
#pragma unroll
        for (int k = 0; k < DIM; ++k) t += p[k] * W2[k * DIM + j];
        z += t * W3[j];
    }
    out[g] = 1.f / (1.f + expf(-z));
}

// ---------------------------------------------------------------------------
// Workspace (bytes):
//   h1     [0,         2000000)    100k x 10 fp16 (L2-resident)
//   pk     [2000000,  27624576)    391 buckets x 16384 slots x 4B
//   r      [27624576, 29624576)    100k x 10 fp16 (L2-resident)
//   part   [29624576, 45639936)    1564 x 2560 f32
//   cnt    [45639936, 45641500)    391 int   \  zeroed by one 4128B memset
//   sums   [45641504, 45644064)    640 f32   /
//   bound  [45644064, 45644324)    65 int
// ---------------------------------------------------------------------------
extern "C" void kernel_launch(void* const* d_in, const int* in_sizes, int n_in,
                              void* d_out, int out_size, void* d_ws, size_t ws_size,
                              hipStream_t stream) {
    const float* feat = (const float*)d_in[0];
    const float* W1   = (const float*)d_in[1];
    const float* W2   = (const float*)d_in[2];
    const float* W3   = (const float*)d_in[3];
    const int*   src  = (const int*)d_in[4];
    const int*   dst  = (const int*)d_in[5];
    const int*   gids = (const int*)d_in[6];
    float*       out  = (float*)d_out;

    char* ws = (char*)d_ws;
    __half* h1    = (__half*)(ws);
    int*    pk    = (int*)(ws + 2000000);
    __half* r     = (__half*)(ws + 27624576);
    float*  part  = (float*)(ws + 29624576);
    int*    cnt   = (int*)(ws + 45639936);
    float*  sums  = (float*)(ws + 45641504);
    int*    bound = (int*)(ws + 45644064);

    // zero cnt (391 int) + pad + sums (640 f32) in one tiny DMA
    hipMemsetAsync(ws + 45639936, 0, 4128, stream);

    k_front<<<PLACE_BLOCKS + GEMM_BLOCKS, 512, 0, stream>>>(feat, W1, h1, gids, bound,
                                                            src, dst, cnt, pk);
    k_spmm1     <<<NCHUNK, 512, 0, stream>>>(h1, cnt, pk, part);
    k_merge_relu<<<NB, 256, 0, stream>>>(part, r);
    k_pass2     <<<NCHUNK2, 512, 0, stream>>>(r, cnt, pk, bound, sums);

    k_final<<<1, 64, 0, stream>>>(sums, bound, W2, W3, out);
}